// Round 4
// baseline (920.587 us; speedup 1.0000x reference)
//
#include <hip/hip_runtime.h>
#include <math.h>

#define NEG_SLOPE 0.2f

typedef __attribute__((ext_vector_type(8))) short bf16x8;
typedef __attribute__((ext_vector_type(4))) float f32x4;

// ---------------- bf16 helpers (RNE) ----------------
__device__ __forceinline__ float b2f(unsigned short u) {
    return __uint_as_float(((unsigned)u) << 16);
}
__device__ __forceinline__ unsigned short f2b(float f) {
    unsigned u = __float_as_uint(f);
    unsigned r = (u + 0x7fffu + ((u >> 16) & 1u)) >> 16;
    return (unsigned short)r;
}

// ---------------- async global->LDS 16B ----------------
__device__ __forceinline__ void async_copy16(const void* g, void* l) {
    __builtin_amdgcn_global_load_lds(
        (const __attribute__((address_space(1))) void*)g,
        (__attribute__((address_space(3))) void*)l, 16, 0, 0);
}

// ============== bf16 MFMA GEMM: C[M][Nc] = A[M][K] @ Bt[Nc][K]^T ==========
// 128x128 tile / 256 threads (4 waves, 2x2), BK=32, 16x16x32 MFMA.
// LDS quads XOR-swizzled by ((row>>1)&3) -> 2-way bank aliasing (free).
__global__ __launch_bounds__(256) void gemm_bf16(
    const unsigned short* __restrict__ A,   // [M][K] bf16
    const unsigned short* __restrict__ Bt,  // [Nc][K] bf16 (pre-transposed)
    unsigned short* __restrict__ C,         // [M][Nc] bf16
    int M, int K, int Nc)
{
    __shared__ unsigned short As[128 * 32];
    __shared__ unsigned short Bs[128 * 32];
    const int tid = threadIdx.x;
    const int w = tid >> 6, lane = tid & 63;
    const int tm = blockIdx.x * 128;
    const int tn = blockIdx.y * 128;

    // staging slot mapping: off16 = r*256 + w*64 + lane (16B slots)
    const int off0 = w * 64 + lane;
    const int row0 = off0 >> 2, q0 = off0 & 3;
    const int qg0 = q0 ^ ((row0 >> 1) & 3);
    const int off1 = 256 + w * 64 + lane;
    const int row1 = off1 >> 2, q1 = off1 & 3;
    const int qg1 = q1 ^ ((row1 >> 1) & 3);

    const int ar0 = min(tm + row0, M - 1), ar1 = min(tm + row1, M - 1);
    const int bn0 = min(tn + row0, Nc - 1), bn1 = min(tn + row1, Nc - 1);
    const unsigned short* pa0 = A + (size_t)ar0 * K + qg0 * 8;
    const unsigned short* pa1 = A + (size_t)ar1 * K + qg1 * 8;
    const unsigned short* pb0 = Bt + (size_t)bn0 * K + qg0 * 8;
    const unsigned short* pb1 = Bt + (size_t)bn1 * K + qg1 * 8;
    // wave-uniform LDS bases (HW adds lane*16)
    unsigned short* lA0 = As + (size_t)(w * 64) * 8;
    unsigned short* lA1 = As + (size_t)(256 + w * 64) * 8;
    unsigned short* lB0 = Bs + (size_t)(w * 64) * 8;
    unsigned short* lB1 = Bs + (size_t)(256 + w * 64) * 8;

    // fragment LDS read pointers
    const int m0 = (w & 1) * 64, n0 = (w >> 1) * 64;
    const int fr = lane & 15, Q = lane >> 4;
    const unsigned short* aptr[4];
    const unsigned short* bptr[4];
    #pragma unroll
    for (int i = 0; i < 4; ++i) {
        int ra = m0 + i * 16 + fr;
        aptr[i] = As + (ra * 64 + ((Q ^ ((ra >> 1) & 3)) * 16)) / 2;
        int rb = n0 + i * 16 + fr;
        bptr[i] = Bs + (rb * 64 + ((Q ^ ((rb >> 1) & 3)) * 16)) / 2;
    }

    f32x4 acc[4][4] = {};
    for (int kk = 0; kk < K; kk += 32) {
        async_copy16(pa0 + kk, lA0);
        async_copy16(pa1 + kk, lA1);
        async_copy16(pb0 + kk, lB0);
        async_copy16(pb1 + kk, lB1);
        __syncthreads();
        bf16x8 af[4], bfr[4];
        #pragma unroll
        for (int i = 0; i < 4; ++i) {
            af[i]  = *(const bf16x8*)aptr[i];
            bfr[i] = *(const bf16x8*)bptr[i];
        }
        #pragma unroll
        for (int mi = 0; mi < 4; ++mi)
            #pragma unroll
            for (int ni = 0; ni < 4; ++ni)
                acc[mi][ni] = __builtin_amdgcn_mfma_f32_16x16x32_bf16(
                    af[mi], bfr[ni], acc[mi][ni], 0, 0, 0);
        __syncthreads();
    }

    // epilogue: C/D layout col=lane&15, row=(lane>>4)*4+reg
    #pragma unroll
    for (int mi = 0; mi < 4; ++mi) {
        #pragma unroll
        for (int ni = 0; ni < 4; ++ni) {
            int col = tn + n0 + ni * 16 + fr;
            #pragma unroll
            for (int r = 0; r < 4; ++r) {
                int row = tm + m0 + mi * 16 + Q * 4 + r;
                if (row < M && col < Nc)
                    C[(size_t)row * Nc + col] = f2b(acc[mi][ni][r]);
            }
        }
    }
}

// ---------------- x -> bf16 conversion (+ fold in deg zeroing) ------------
__global__ __launch_bounds__(256) void cvt_f2b_degzero(
    const float* __restrict__ in, unsigned short* __restrict__ outp,
    int total4, int* __restrict__ deg, int n)
{
    int i = blockIdx.x * 256 + threadIdx.x;
    if (i < n) deg[i] = 0;
    if (i >= total4) return;
    float4 v = ((const float4*)in)[i];
    ushort4 o = make_ushort4(f2b(v.x), f2b(v.y), f2b(v.z), f2b(v.w));
    ((ushort4*)outp)[i] = o;
}

// ---- all 4 layers' weights -> transposed concatenated bf16 in one pass ---
// WT layout (shorts): L0 @ 0 (1024*512), L1 @ 524288 (256*512),
//                     L2 @ 655360 (256*512), L3 @ 786432 (256*64)
__global__ __launch_bounds__(256) void cvt_wt_all(
    const float* __restrict__ Wl0, const float* __restrict__ Wr0,
    const float* __restrict__ Wl1, const float* __restrict__ Wr1,
    const float* __restrict__ Wl2, const float* __restrict__ Wr2,
    const float* __restrict__ Wl3, const float* __restrict__ Wr3,
    unsigned short* __restrict__ WT)
{
    int id = blockIdx.x * 256 + threadIdx.x;
    const float *Wl, *Wr; int fin, HC, local; unsigned short* dst;
    if (id < 524288)      { Wl = Wl0; Wr = Wr0; fin = 1024; HC = 256; dst = WT;          local = id; }
    else if (id < 655360) { Wl = Wl1; Wr = Wr1; fin = 256;  HC = 256; dst = WT + 524288; local = id - 524288; }
    else if (id < 786432) { Wl = Wl2; Wr = Wr2; fin = 256;  HC = 256; dst = WT + 655360; local = id - 655360; }
    else if (id < 802816) { Wl = Wl3; Wr = Wr3; fin = 256;  HC = 32;  dst = WT + 786432; local = id - 786432; }
    else return;
    int n = local / fin, k = local - n * fin;
    float v = (n < HC) ? Wl[(size_t)k * HC + n] : Wr[(size_t)k * HC + (n - HC)];
    dst[local] = f2b(v);
}

// ======================= CSR construction (per call) ======================
__global__ __launch_bounds__(256) void deg_count(
    const int* __restrict__ ei, int* __restrict__ deg, int E0, int E)
{
    int e = blockIdx.x * 256 + threadIdx.x;
    if (e >= E) return;
    int d = (e < E0) ? ei[E0 + e] : e - E0;
    atomicAdd(deg + d, 1);
}

__global__ __launch_bounds__(256) void scan_blocks(
    const int* __restrict__ deg, int* __restrict__ rp,
    int* __restrict__ bsums, int n)
{
    __shared__ int sm[256];
    int base = blockIdx.x * 1024;
    int t = threadIdx.x;
    int i0 = base + t * 4;
    int v0 = (i0 + 0 < n) ? deg[i0 + 0] : 0;
    int v1 = (i0 + 1 < n) ? deg[i0 + 1] : 0;
    int v2 = (i0 + 2 < n) ? deg[i0 + 2] : 0;
    int v3 = (i0 + 3 < n) ? deg[i0 + 3] : 0;
    int tsum = v0 + v1 + v2 + v3;
    sm[t] = tsum;
    __syncthreads();
    for (int off = 1; off < 256; off <<= 1) {
        int val = (t >= off) ? sm[t - off] : 0;
        __syncthreads();
        sm[t] += val;
        __syncthreads();
    }
    int exb = sm[t] - tsum;
    if (t == 255) bsums[blockIdx.x] = sm[255];
    if (i0 + 0 < n) rp[i0 + 0] = exb;
    if (i0 + 1 < n) rp[i0 + 1] = exb + v0;
    if (i0 + 2 < n) rp[i0 + 2] = exb + v0 + v1;
    if (i0 + 3 < n) rp[i0 + 3] = exb + v0 + v1 + v2;
}

__global__ void scan_bsums(int* __restrict__ bsums, int nb)
{
    __shared__ int sm[64];
    int t = threadIdx.x;
    int v = (t < nb) ? bsums[t] : 0;
    sm[t] = v;
    __syncthreads();
    for (int off = 1; off < 64; off <<= 1) {
        int val = (t >= off) ? sm[t - off] : 0;
        __syncthreads();
        sm[t] += val;
        __syncthreads();
    }
    if (t < nb) bsums[t] = sm[t] - v;
}

__global__ __launch_bounds__(256) void scan_finalize(
    int* __restrict__ rp, int* __restrict__ cur,
    const int* __restrict__ bsums, int n)
{
    int i = blockIdx.x * 256 + threadIdx.x;
    if (i < n) {
        int v = rp[i] + bsums[i >> 10];
        rp[i] = v;
        cur[i] = v;
    }
}

__global__ __launch_bounds__(256) void csr_fill(
    const int* __restrict__ ei, int* __restrict__ cur,
    int* __restrict__ csrc, int E0, int E)
{
    int e = blockIdx.x * 256 + threadIdx.x;
    if (e >= E) return;
    int s, d;
    if (e < E0) { s = ei[e]; d = ei[E0 + e]; } else { s = e - E0; d = s; }
    int pos = atomicAdd(cur + d, 1);
    csrc[pos] = s;
}

// ====== fused GATv2 attention + aggregation, HC=256 (H=2,C=128), bf16 =====
// One wave per dst node; lanes 0-31 head 0, 32-63 head 1; 4 features/lane.
// Chunked 16-deep gather prefetch -> registers, then serial online softmax.
#define CH 16
__global__ __launch_bounds__(256) void aggr_csr_256(
    const unsigned short* __restrict__ xlr,
    const float* __restrict__ att, const float* __restrict__ bias,
    const int* __restrict__ csrc, const int* __restrict__ rp,
    const int* __restrict__ deg, unsigned short* __restrict__ outb, int N)
{
    int node = blockIdx.x * 4 + (threadIdx.x >> 6);
    if (node >= N) return;
    int lane = threadIdx.x & 63;
    ushort4 bu = *(const ushort4*)(xlr + (size_t)node * 512 + 256 + lane * 4);
    float bx = b2f(bu.x), by = b2f(bu.y), bz = b2f(bu.z), bw = b2f(bu.w);
    float4 wv = *(const float4*)(att + lane * 4);
    int start = rp[node];
    int g = deg[node];
    float m = -INFINITY, l = 0.f;
    float4 acc = make_float4(0.f, 0.f, 0.f, 0.f);
    for (int j0 = 0; j0 < g; j0 += CH) {
        ushort4 rb[CH];
        #pragma unroll
        for (int t = 0; t < CH; ++t) {
            if (j0 + t < g) {    // wave-uniform per node-wave
                int s = csrc[start + j0 + t];
                rb[t] = *(const ushort4*)(xlr + (size_t)s * 512 + lane * 4);
            }
        }
        #pragma unroll
        for (int t = 0; t < CH; ++t) {
            if (j0 + t >= g) break;
            float ax = b2f(rb[t].x), ay = b2f(rb[t].y);
            float az = b2f(rb[t].z), aw = b2f(rb[t].w);
            float y, dot = 0.f;
            y = ax + bx; y = (y > 0.f) ? y : NEG_SLOPE * y; dot += y * wv.x;
            y = ay + by; y = (y > 0.f) ? y : NEG_SLOPE * y; dot += y * wv.y;
            y = az + bz; y = (y > 0.f) ? y : NEG_SLOPE * y; dot += y * wv.z;
            y = aw + bw; y = (y > 0.f) ? y : NEG_SLOPE * y; dot += y * wv.w;
            #pragma unroll
            for (int mk = 1; mk < 32; mk <<= 1) dot += __shfl_xor(dot, mk, 64);
            float mn = fmaxf(m, dot);
            float scale = __expf(m - mn);   // first iter: exp(-inf) = 0
            float p = __expf(dot - mn);
            l = l * scale + p;
            acc.x = acc.x * scale + p * ax;
            acc.y = acc.y * scale + p * ay;
            acc.z = acc.z * scale + p * az;
            acc.w = acc.w * scale + p * aw;
            m = mn;
        }
    }
    float inv = 1.f / l;
    float4 bi = *(const float4*)(bias + lane * 4);
    ushort4 o = make_ushort4(f2b(acc.x * inv + bi.x), f2b(acc.y * inv + bi.y),
                             f2b(acc.z * inv + bi.z), f2b(acc.w * inv + bi.w));
    *(ushort4*)(outb + (size_t)node * 256 + lane * 4) = o;
}

// ===== fused attention + aggregation, HC=32 (H=1,C=32), final layer =======
// 8 lanes per dst node; reads bf16 xlr [N][64] (xl=+0, xr=+32), writes fp32.
__global__ __launch_bounds__(256) void aggr_csr_32(
    const unsigned short* __restrict__ xlr,
    const float* __restrict__ att, const float* __restrict__ bias,
    const int* __restrict__ csrc, const int* __restrict__ rp,
    const int* __restrict__ deg, float* __restrict__ out, int N)
{
    int node = blockIdx.x * 32 + (threadIdx.x >> 3);
    if (node >= N) return;
    int lane8 = threadIdx.x & 7;
    ushort4 bu = *(const ushort4*)(xlr + (size_t)node * 64 + 32 + lane8 * 4);
    float bx = b2f(bu.x), by = b2f(bu.y), bz = b2f(bu.z), bw = b2f(bu.w);
    float4 wv = *(const float4*)(att + lane8 * 4);
    int start = rp[node];
    int g = deg[node];
    float m = -INFINITY, l = 0.f;
    float4 acc = make_float4(0.f, 0.f, 0.f, 0.f);
    for (int j0 = 0; j0 < g; j0 += CH) {
        ushort4 rb[CH];
        #pragma unroll
        for (int t = 0; t < CH; ++t) {
            if (j0 + t < g) {    // divergent across node-subgroups; exec-masked
                int s = csrc[start + j0 + t];
                rb[t] = *(const ushort4*)(xlr + (size_t)s * 64 + lane8 * 4);
            }
        }
        #pragma unroll
        for (int t = 0; t < CH; ++t) {
            if (j0 + t >= g) break;
            float ax = b2f(rb[t].x), ay = b2f(rb[t].y);
            float az = b2f(rb[t].z), aw = b2f(rb[t].w);
            float y, dot = 0.f;
            y = ax + bx; y = (y > 0.f) ? y : NEG_SLOPE * y; dot += y * wv.x;
            y = ay + by; y = (y > 0.f) ? y : NEG_SLOPE * y; dot += y * wv.y;
            y = az + bz; y = (y > 0.f) ? y : NEG_SLOPE * y; dot += y * wv.z;
            y = aw + bw; y = (y > 0.f) ? y : NEG_SLOPE * y; dot += y * wv.w;
            #pragma unroll
            for (int mk = 1; mk < 8; mk <<= 1) dot += __shfl_xor(dot, mk, 64);
            float mn = fmaxf(m, dot);
            float scale = __expf(m - mn);
            float p = __expf(dot - mn);
            l = l * scale + p;
            acc.x = acc.x * scale + p * ax;
            acc.y = acc.y * scale + p * ay;
            acc.z = acc.z * scale + p * az;
            acc.w = acc.w * scale + p * aw;
            m = mn;
        }
    }
    float inv = 1.f / l;
    float4 bi = *(const float4*)(bias + lane8 * 4);
    float4 o;
    o.x = acc.x * inv + bi.x;
    o.y = acc.y * inv + bi.y;
    o.z = acc.z * inv + bi.z;
    o.w = acc.w * inv + bi.w;
    *(float4*)(out + (size_t)node * 32 + lane8 * 4) = o;
}

extern "C" void kernel_launch(void* const* d_in, const int* in_sizes, int n_in,
                              void* d_out, int out_size, void* d_ws, size_t ws_size,
                              hipStream_t stream)
{
    const float* x  = (const float*)d_in[0];
    const int*   ei = (const int*)d_in[1];
    const float* Wl[4]   = {(const float*)d_in[2], (const float*)d_in[6], (const float*)d_in[10], (const float*)d_in[14]};
    const float* Wr[4]   = {(const float*)d_in[3], (const float*)d_in[7], (const float*)d_in[11], (const float*)d_in[15]};
    const float* attw[4] = {(const float*)d_in[4], (const float*)d_in[8], (const float*)d_in[12], (const float*)d_in[16]};
    const float* bias[4] = {(const float*)d_in[5], (const float*)d_in[9], (const float*)d_in[13], (const float*)d_in[17]};
    float* outp = (float*)d_out;

    const int N  = in_sizes[0] / 1024;   // 50000
    const int E0 = in_sizes[1] / 2;      // 400000
    const int E  = E0 + N;               // +self loops
    const int NB = (N + 1023) / 1024;

    // workspace layout
    int* deg   = (int*)d_ws;                         // N
    int* rp    = deg + N;                            // N
    int* cur   = rp + N;                             // N
    int* bsums = cur + N;                            // 64
    int* csrc  = bsums + 64;                         // E
    unsigned short* WT  = (unsigned short*)(csrc + E);      // 802816 shorts
    unsigned short* xb  = WT + 802816;                      // N*1024 bf16
    unsigned short* hb  = xb;                               // alias: xb dead after L0 GEMM
    unsigned short* xlr = xb + (size_t)N * 1024;            // N*512 bf16
    const int wtOff[4] = {0, 524288, 655360, 786432};

    dim3 blk(256);

    // ---- x -> bf16 (+ deg zero), CSR build, weight conversion ----
    cvt_f2b_degzero<<<((size_t)N * 1024 / 4 + 255) / 256, blk, 0, stream>>>(
        x, xb, N * 1024 / 4, deg, N);
    deg_count<<<(E + 255) / 256, blk, 0, stream>>>(ei, deg, E0, E);
    scan_blocks<<<NB, blk, 0, stream>>>(deg, rp, bsums, N);
    scan_bsums<<<1, 64, 0, stream>>>(bsums, NB);
    scan_finalize<<<(N + 255) / 256, blk, 0, stream>>>(rp, cur, bsums, N);
    csr_fill<<<(E + 255) / 256, blk, 0, stream>>>(ei, cur, csrc, E0, E);
    cvt_wt_all<<<(802816 + 255) / 256, blk, 0, stream>>>(
        Wl[0], Wr[0], Wl[1], Wr[1], Wl[2], Wr[2], Wl[3], Wr[3], WT);

    const int gm = (N + 127) / 128;
    for (int l = 0; l < 4; ++l) {
        const int HC  = (l == 3) ? 32 : 256;
        const int fin = (l == 0) ? 1024 : 256;
        const int Nc  = 2 * HC;
        const unsigned short* Ain = (l == 0) ? xb : hb;

        gemm_bf16<<<dim3(gm, (Nc + 127) / 128), blk, 0, stream>>>(
            Ain, WT + wtOff[l], xlr, N, fin, Nc);

        if (l < 3) {
            aggr_csr_256<<<(N + 3) / 4, blk, 0, stream>>>(
                xlr, attw[l], bias[l], csrc, rp, deg, hb, N);
        } else {
            aggr_csr_32<<<(N + 31) / 32, blk, 0, stream>>>(
                xlr, attw[l], bias[l], csrc, rp, deg, outp, N);
        }
    }
}

// Round 5
// 751.741 us; speedup vs baseline: 1.2246x; 1.2246x over previous
//
#include <hip/hip_runtime.h>
#include <math.h>

#define NEG_SLOPE 0.2f

typedef __attribute__((ext_vector_type(8))) short bf16x8;
typedef __attribute__((ext_vector_type(4))) float f32x4;

// ---------------- bf16 helpers (RNE) ----------------
__device__ __forceinline__ float b2f(unsigned short u) {
    return __uint_as_float(((unsigned)u) << 16);
}
__device__ __forceinline__ unsigned short f2b(float f) {
    unsigned u = __float_as_uint(f);
    unsigned r = (u + 0x7fffu + ((u >> 16) & 1u)) >> 16;
    return (unsigned short)r;
}

// ---------------- async global->LDS 16B ----------------
__device__ __forceinline__ void async_copy16(const void* g, void* l) {
    __builtin_amdgcn_global_load_lds(
        (const __attribute__((address_space(1))) void*)g,
        (__attribute__((address_space(3))) void*)l, 16, 0, 0);
}

// ============== bf16 MFMA GEMM: C[M][Nc] = A[M][K] @ Bt[Nc][K]^T ==========
// 128x128 tile / 256 threads (4 waves, 2x2), BK=32, 16x16x32 MFMA.
// LDS quads XOR-swizzled by ((row>>1)&3) -> 2-way bank aliasing (free).
__global__ __launch_bounds__(256) void gemm_bf16(
    const unsigned short* __restrict__ A,   // [M][K] bf16
    const unsigned short* __restrict__ Bt,  // [Nc][K] bf16 (pre-transposed)
    unsigned short* __restrict__ C,         // [M][Nc] bf16
    int M, int K, int Nc)
{
    __shared__ unsigned short As[128 * 32];
    __shared__ unsigned short Bs[128 * 32];
    const int tid = threadIdx.x;
    const int w = tid >> 6, lane = tid & 63;
    const int tm = blockIdx.x * 128;
    const int tn = blockIdx.y * 128;

    // staging slot mapping: off16 = r*256 + w*64 + lane (16B slots)
    const int off0 = w * 64 + lane;
    const int row0 = off0 >> 2, q0 = off0 & 3;
    const int qg0 = q0 ^ ((row0 >> 1) & 3);
    const int off1 = 256 + w * 64 + lane;
    const int row1 = off1 >> 2, q1 = off1 & 3;
    const int qg1 = q1 ^ ((row1 >> 1) & 3);

    const int ar0 = min(tm + row0, M - 1), ar1 = min(tm + row1, M - 1);
    const int bn0 = min(tn + row0, Nc - 1), bn1 = min(tn + row1, Nc - 1);
    const unsigned short* pa0 = A + (size_t)ar0 * K + qg0 * 8;
    const unsigned short* pa1 = A + (size_t)ar1 * K + qg1 * 8;
    const unsigned short* pb0 = Bt + (size_t)bn0 * K + qg0 * 8;
    const unsigned short* pb1 = Bt + (size_t)bn1 * K + qg1 * 8;
    // wave-uniform LDS bases (HW adds lane*16)
    unsigned short* lA0 = As + (size_t)(w * 64) * 8;
    unsigned short* lA1 = As + (size_t)(256 + w * 64) * 8;
    unsigned short* lB0 = Bs + (size_t)(w * 64) * 8;
    unsigned short* lB1 = Bs + (size_t)(256 + w * 64) * 8;

    // fragment LDS read pointers
    const int m0 = (w & 1) * 64, n0 = (w >> 1) * 64;
    const int fr = lane & 15, Q = lane >> 4;
    const unsigned short* aptr[4];
    const unsigned short* bptr[4];
    #pragma unroll
    for (int i = 0; i < 4; ++i) {
        int ra = m0 + i * 16 + fr;
        aptr[i] = As + (ra * 64 + ((Q ^ ((ra >> 1) & 3)) * 16)) / 2;
        int rb = n0 + i * 16 + fr;
        bptr[i] = Bs + (rb * 64 + ((Q ^ ((rb >> 1) & 3)) * 16)) / 2;
    }

    f32x4 acc[4][4] = {};
    for (int kk = 0; kk < K; kk += 32) {
        async_copy16(pa0 + kk, lA0);
        async_copy16(pa1 + kk, lA1);
        async_copy16(pb0 + kk, lB0);
        async_copy16(pb1 + kk, lB1);
        __syncthreads();
        bf16x8 af[4], bfr[4];
        #pragma unroll
        for (int i = 0; i < 4; ++i) {
            af[i]  = *(const bf16x8*)aptr[i];
            bfr[i] = *(const bf16x8*)bptr[i];
        }
        #pragma unroll
        for (int mi = 0; mi < 4; ++mi)
            #pragma unroll
            for (int ni = 0; ni < 4; ++ni)
                acc[mi][ni] = __builtin_amdgcn_mfma_f32_16x16x32_bf16(
                    af[mi], bfr[ni], acc[mi][ni], 0, 0, 0);
        __syncthreads();
    }

    // epilogue: C/D layout col=lane&15, row=(lane>>4)*4+reg
    #pragma unroll
    for (int mi = 0; mi < 4; ++mi) {
        #pragma unroll
        for (int ni = 0; ni < 4; ++ni) {
            int col = tn + n0 + ni * 16 + fr;
            #pragma unroll
            for (int r = 0; r < 4; ++r) {
                int row = tm + m0 + mi * 16 + Q * 4 + r;
                if (row < M && col < Nc)
                    C[(size_t)row * Nc + col] = f2b(acc[mi][ni][r]);
            }
        }
    }
}

// ---------------- x -> bf16 conversion (+ fold in deg zeroing) ------------
__global__ __launch_bounds__(256) void cvt_f2b_degzero(
    const float* __restrict__ in, unsigned short* __restrict__ outp,
    int total4, int* __restrict__ deg, int n)
{
    int i = blockIdx.x * 256 + threadIdx.x;
    if (i < n) deg[i] = 0;
    if (i >= total4) return;
    float4 v = ((const float4*)in)[i];
    ushort4 o = make_ushort4(f2b(v.x), f2b(v.y), f2b(v.z), f2b(v.w));
    ((ushort4*)outp)[i] = o;
}

// ---- all 4 layers' weights -> transposed concatenated bf16 in one pass ---
// WT layout (shorts): L0 @ 0 (1024*512), L1 @ 524288 (256*512),
//                     L2 @ 655360 (256*512), L3 @ 786432 (256*64)
__global__ __launch_bounds__(256) void cvt_wt_all(
    const float* __restrict__ Wl0, const float* __restrict__ Wr0,
    const float* __restrict__ Wl1, const float* __restrict__ Wr1,
    const float* __restrict__ Wl2, const float* __restrict__ Wr2,
    const float* __restrict__ Wl3, const float* __restrict__ Wr3,
    unsigned short* __restrict__ WT)
{
    int id = blockIdx.x * 256 + threadIdx.x;
    const float *Wl, *Wr; int fin, HC, local; unsigned short* dst;
    if (id < 524288)      { Wl = Wl0; Wr = Wr0; fin = 1024; HC = 256; dst = WT;          local = id; }
    else if (id < 655360) { Wl = Wl1; Wr = Wr1; fin = 256;  HC = 256; dst = WT + 524288; local = id - 524288; }
    else if (id < 786432) { Wl = Wl2; Wr = Wr2; fin = 256;  HC = 256; dst = WT + 655360; local = id - 655360; }
    else if (id < 802816) { Wl = Wl3; Wr = Wr3; fin = 256;  HC = 32;  dst = WT + 786432; local = id - 786432; }
    else return;
    int n = local / fin, k = local - n * fin;
    float v = (n < HC) ? Wl[(size_t)k * HC + n] : Wr[(size_t)k * HC + (n - HC)];
    dst[local] = f2b(v);
}

// ======================= CSR construction (per call) ======================
__global__ __launch_bounds__(256) void deg_count(
    const int* __restrict__ ei, int* __restrict__ deg, int E0, int E)
{
    int e = blockIdx.x * 256 + threadIdx.x;
    if (e >= E) return;
    int d = (e < E0) ? ei[E0 + e] : e - E0;
    atomicAdd(deg + d, 1);
}

__global__ __launch_bounds__(256) void scan_blocks(
    const int* __restrict__ deg, int* __restrict__ rp,
    int* __restrict__ bsums, int n)
{
    __shared__ int sm[256];
    int base = blockIdx.x * 1024;
    int t = threadIdx.x;
    int i0 = base + t * 4;
    int v0 = (i0 + 0 < n) ? deg[i0 + 0] : 0;
    int v1 = (i0 + 1 < n) ? deg[i0 + 1] : 0;
    int v2 = (i0 + 2 < n) ? deg[i0 + 2] : 0;
    int v3 = (i0 + 3 < n) ? deg[i0 + 3] : 0;
    int tsum = v0 + v1 + v2 + v3;
    sm[t] = tsum;
    __syncthreads();
    for (int off = 1; off < 256; off <<= 1) {
        int val = (t >= off) ? sm[t - off] : 0;
        __syncthreads();
        sm[t] += val;
        __syncthreads();
    }
    int exb = sm[t] - tsum;
    if (t == 255) bsums[blockIdx.x] = sm[255];
    if (i0 + 0 < n) rp[i0 + 0] = exb;
    if (i0 + 1 < n) rp[i0 + 1] = exb + v0;
    if (i0 + 2 < n) rp[i0 + 2] = exb + v0 + v1;
    if (i0 + 3 < n) rp[i0 + 3] = exb + v0 + v1 + v2;
}

__global__ void scan_bsums(int* __restrict__ bsums, int nb)
{
    __shared__ int sm[64];
    int t = threadIdx.x;
    int v = (t < nb) ? bsums[t] : 0;
    sm[t] = v;
    __syncthreads();
    for (int off = 1; off < 64; off <<= 1) {
        int val = (t >= off) ? sm[t - off] : 0;
        __syncthreads();
        sm[t] += val;
        __syncthreads();
    }
    if (t < nb) bsums[t] = sm[t] - v;
}

__global__ __launch_bounds__(256) void scan_finalize(
    int* __restrict__ rp, int* __restrict__ cur,
    const int* __restrict__ bsums, int n)
{
    int i = blockIdx.x * 256 + threadIdx.x;
    if (i < n) {
        int v = rp[i] + bsums[i >> 10];
        rp[i] = v;
        cur[i] = v;
    }
}

__global__ __launch_bounds__(256) void csr_fill(
    const int* __restrict__ ei, int* __restrict__ cur,
    int* __restrict__ csrc, int E0, int E)
{
    int e = blockIdx.x * 256 + threadIdx.x;
    if (e >= E) return;
    int s, d;
    if (e < E0) { s = ei[e]; d = ei[E0 + e]; } else { s = e - E0; d = s; }
    int pos = atomicAdd(cur + d, 1);
    csrc[pos] = s;
}

// ========== chunked online-softmax update (unconditional loads) ===========
// T rows prefetched into registers (no conditional writes -> SROA-safe),
// then consumed serially with online softmax. STRIDE = row stride (shorts),
// SHW = butterfly width (head reduction).
template<int T, int STRIDE, int SHW>
__device__ __forceinline__ void gat_chunk(
    const unsigned short* __restrict__ xlr, const int* __restrict__ cp,
    int laneoff, float bx, float by, float bz, float bw, float4 wv,
    float& m, float& l, float4& acc)
{
    int idx[T];
    #pragma unroll
    for (int t = 0; t < T; ++t) idx[t] = cp[t];
    ushort4 rb[T];
    #pragma unroll
    for (int t = 0; t < T; ++t)
        rb[t] = *(const ushort4*)(xlr + (size_t)idx[t] * STRIDE + laneoff);
    #pragma unroll
    for (int t = 0; t < T; ++t) {
        float ax = b2f(rb[t].x), ay = b2f(rb[t].y);
        float az = b2f(rb[t].z), aw = b2f(rb[t].w);
        float y, dot = 0.f;
        y = ax + bx; y = (y > 0.f) ? y : NEG_SLOPE * y; dot += y * wv.x;
        y = ay + by; y = (y > 0.f) ? y : NEG_SLOPE * y; dot += y * wv.y;
        y = az + bz; y = (y > 0.f) ? y : NEG_SLOPE * y; dot += y * wv.z;
        y = aw + bw; y = (y > 0.f) ? y : NEG_SLOPE * y; dot += y * wv.w;
        #pragma unroll
        for (int mk = 1; mk < SHW; mk <<= 1) dot += __shfl_xor(dot, mk, 64);
        float mn = fmaxf(m, dot);
        float scale = __expf(m - mn);   // first edge: exp(-inf) = 0
        float p = __expf(dot - mn);
        l = l * scale + p;
        acc.x = acc.x * scale + p * ax;
        acc.y = acc.y * scale + p * ay;
        acc.z = acc.z * scale + p * az;
        acc.w = acc.w * scale + p * aw;
        m = mn;
    }
}

// ====== fused GATv2 attention + aggregation, HC=256 (H=2,C=128), bf16 =====
// One wave per dst node; lanes 0-31 head 0, 32-63 head 1; 4 features/lane.
// Power-of-2 chunk ladder: loads exactly deg rows, up to 8 gathers in flight.
__global__ __launch_bounds__(256) void aggr_csr_256(
    const unsigned short* __restrict__ xlr,
    const float* __restrict__ att, const float* __restrict__ bias,
    const int* __restrict__ csrc, const int* __restrict__ rp,
    const int* __restrict__ deg, unsigned short* __restrict__ outb, int N)
{
    int node = blockIdx.x * 4 + (threadIdx.x >> 6);
    if (node >= N) return;
    int lane = threadIdx.x & 63;
    int laneoff = lane * 4;
    ushort4 bu = *(const ushort4*)(xlr + (size_t)node * 512 + 256 + laneoff);
    float bx = b2f(bu.x), by = b2f(bu.y), bz = b2f(bu.z), bw = b2f(bu.w);
    float4 wv = *(const float4*)(att + laneoff);
    int start = rp[node];
    int g = deg[node];
    const int* cp = csrc + start;
    float m = -INFINITY, l = 0.f;
    float4 acc = make_float4(0.f, 0.f, 0.f, 0.f);
    int j = 0;
    while (j + 8 <= g) {
        gat_chunk<8, 512, 32>(xlr, cp + j, laneoff, bx, by, bz, bw, wv, m, l, acc);
        j += 8;
    }
    if (j + 4 <= g) {
        gat_chunk<4, 512, 32>(xlr, cp + j, laneoff, bx, by, bz, bw, wv, m, l, acc);
        j += 4;
    }
    if (j + 2 <= g) {
        gat_chunk<2, 512, 32>(xlr, cp + j, laneoff, bx, by, bz, bw, wv, m, l, acc);
        j += 2;
    }
    if (j < g) {
        gat_chunk<1, 512, 32>(xlr, cp + j, laneoff, bx, by, bz, bw, wv, m, l, acc);
    }
    float inv = 1.f / l;
    float4 bi = *(const float4*)(bias + laneoff);
    ushort4 o = make_ushort4(f2b(acc.x * inv + bi.x), f2b(acc.y * inv + bi.y),
                             f2b(acc.z * inv + bi.z), f2b(acc.w * inv + bi.w));
    *(ushort4*)(outb + (size_t)node * 256 + laneoff) = o;
}

// ===== fused attention + aggregation, HC=32 (H=1,C=32), final layer =======
// 8 lanes per dst node; reads bf16 xlr [N][64] (xl=+0, xr=+32), writes fp32.
// Ladder branches diverge across the 8 node-subgroups -> exec-masked, OK.
__global__ __launch_bounds__(256) void aggr_csr_32(
    const unsigned short* __restrict__ xlr,
    const float* __restrict__ att, const float* __restrict__ bias,
    const int* __restrict__ csrc, const int* __restrict__ rp,
    const int* __restrict__ deg, float* __restrict__ out, int N)
{
    int node = blockIdx.x * 32 + (threadIdx.x >> 3);
    if (node >= N) return;
    int lane8 = threadIdx.x & 7;
    int laneoff = lane8 * 4;
    ushort4 bu = *(const ushort4*)(xlr + (size_t)node * 64 + 32 + laneoff);
    float bx = b2f(bu.x), by = b2f(bu.y), bz = b2f(bu.z), bw = b2f(bu.w);
    float4 wv = *(const float4*)(att + laneoff);
    int start = rp[node];
    int g = deg[node];
    const int* cp = csrc + start;
    float m = -INFINITY, l = 0.f;
    float4 acc = make_float4(0.f, 0.f, 0.f, 0.f);
    int j = 0;
    while (j + 8 <= g) {
        gat_chunk<8, 64, 8>(xlr, cp + j, laneoff, bx, by, bz, bw, wv, m, l, acc);
        j += 8;
    }
    if (j + 4 <= g) {
        gat_chunk<4, 64, 8>(xlr, cp + j, laneoff, bx, by, bz, bw, wv, m, l, acc);
        j += 4;
    }
    if (j + 2 <= g) {
        gat_chunk<2, 64, 8>(xlr, cp + j, laneoff, bx, by, bz, bw, wv, m, l, acc);
        j += 2;
    }
    if (j < g) {
        gat_chunk<1, 64, 8>(xlr, cp + j, laneoff, bx, by, bz, bw, wv, m, l, acc);
    }
    float inv = 1.f / l;
    float4 bi = *(const float4*)(bias + laneoff);
    float4 o;
    o.x = acc.x * inv + bi.x;
    o.y = acc.y * inv + bi.y;
    o.z = acc.z * inv + bi.z;
    o.w = acc.w * inv + bi.w;
    *(float4*)(out + (size_t)node * 32 + laneoff) = o;
}

extern "C" void kernel_launch(void* const* d_in, const int* in_sizes, int n_in,
                              void* d_out, int out_size, void* d_ws, size_t ws_size,
                              hipStream_t stream)
{
    const float* x  = (const float*)d_in[0];
    const int*   ei = (const int*)d_in[1];
    const float* Wl[4]   = {(const float*)d_in[2], (const float*)d_in[6], (const float*)d_in[10], (const float*)d_in[14]};
    const float* Wr[4]   = {(const float*)d_in[3], (const float*)d_in[7], (const float*)d_in[11], (const float*)d_in[15]};
    const float* attw[4] = {(const float*)d_in[4], (const float*)d_in[8], (const float*)d_in[12], (const float*)d_in[16]};
    const float* bias[4] = {(const float*)d_in[5], (const float*)d_in[9], (const float*)d_in[13], (const float*)d_in[17]};
    float* outp = (float*)d_out;

    const int N  = in_sizes[0] / 1024;   // 50000
    const int E0 = in_sizes[1] / 2;      // 400000
    const int E  = E0 + N;               // +self loops
    const int NB = (N + 1023) / 1024;

    // workspace layout
    int* deg   = (int*)d_ws;                         // N
    int* rp    = deg + N;                            // N
    int* cur   = rp + N;                             // N
    int* bsums = cur + N;                            // 64
    int* csrc  = bsums + 64;                         // E
    unsigned short* WT  = (unsigned short*)(csrc + E);      // 802816 shorts
    unsigned short* xb  = WT + 802816;                      // N*1024 bf16
    unsigned short* hb  = xb;                               // alias: xb dead after L0 GEMM
    unsigned short* xlr = xb + (size_t)N * 1024;            // N*512 bf16
    const int wtOff[4] = {0, 524288, 655360, 786432};

    dim3 blk(256);

    // ---- x -> bf16 (+ deg zero), CSR build, weight conversion ----
    cvt_f2b_degzero<<<((size_t)N * 1024 / 4 + 255) / 256, blk, 0, stream>>>(
        x, xb, N * 1024 / 4, deg, N);
    deg_count<<<(E + 255) / 256, blk, 0, stream>>>(ei, deg, E0, E);
    scan_blocks<<<NB, blk, 0, stream>>>(deg, rp, bsums, N);
    scan_bsums<<<1, 64, 0, stream>>>(bsums, NB);
    scan_finalize<<<(N + 255) / 256, blk, 0, stream>>>(rp, cur, bsums, N);
    csr_fill<<<(E + 255) / 256, blk, 0, stream>>>(ei, cur, csrc, E0, E);
    cvt_wt_all<<<(802816 + 255) / 256, blk, 0, stream>>>(
        Wl[0], Wr[0], Wl[1], Wr[1], Wl[2], Wr[2], Wl[3], Wr[3], WT);

    const int gm = (N + 127) / 128;
    for (int l = 0; l < 4; ++l) {
        const int HC  = (l == 3) ? 32 : 256;
        const int fin = (l == 0) ? 1024 : 256;
        const int Nc  = 2 * HC;
        const unsigned short* Ain = (l == 0) ? xb : hb;

        gemm_bf16<<<dim3(gm, (Nc + 127) / 128), blk, 0, stream>>>(
            Ain, WT + wtOff[l], xlr, N, fin, Nc);

        if (l < 3) {
            aggr_csr_256<<<(N + 3) / 4, blk, 0, stream>>>(
                xlr, attw[l], bias[l], csrc, rp, deg, hb, N);
        } else {
            aggr_csr_32<<<(N + 31) / 32, blk, 0, stream>>>(
                xlr, attw[l], bias[l], csrc, rp, deg, outp, N);
        }
    }
}

// Round 6
// 705.951 us; speedup vs baseline: 1.3040x; 1.0649x over previous
//
#include <hip/hip_runtime.h>
#include <math.h>

#define NEG_SLOPE 0.2f

typedef __attribute__((ext_vector_type(8))) short bf16x8;
typedef __attribute__((ext_vector_type(4))) float f32x4;
typedef __attribute__((ext_vector_type(8))) unsigned short u16x8;

// ---------------- bf16 helpers (RNE) ----------------
__device__ __forceinline__ float b2f(unsigned short u) {
    return __uint_as_float(((unsigned)u) << 16);
}
__device__ __forceinline__ unsigned short f2b(float f) {
    unsigned u = __float_as_uint(f);
    unsigned r = (u + 0x7fffu + ((u >> 16) & 1u)) >> 16;
    return (unsigned short)r;
}

// ---------------- async global->LDS 16B ----------------
__device__ __forceinline__ void async_copy16(const void* g, void* l) {
    __builtin_amdgcn_global_load_lds(
        (const __attribute__((address_space(1))) void*)g,
        (__attribute__((address_space(3))) void*)l, 16, 0, 0);
}

// ============== bf16 MFMA GEMM: C[M][Nc] = A[M][K] @ Bt[Nc][K]^T ==========
// 128x128 tile / 256 threads (4 waves, 2x2), BK=32, 16x16x32 MFMA.
// LDS quads XOR-swizzled by ((row>>1)&3) -> 2-way bank aliasing (free).
// 1-D grid, XCD-swizzled: xcd = b&7; within an XCD, n-tile cycles fastest so
// the gn blocks sharing an A-strip run back-to-back on the same L2.
__global__ __launch_bounds__(256) void gemm_bf16(
    const unsigned short* __restrict__ A,   // [M][K] bf16
    const unsigned short* __restrict__ Bt,  // [Nc][K] bf16 (pre-transposed)
    unsigned short* __restrict__ C,         // [M][Nc] bf16
    int M, int K, int Nc, int gm, int gn)
{
    __shared__ unsigned short As[128 * 32];
    __shared__ unsigned short Bs[128 * 32];
    const int b = blockIdx.x;
    const int xcd = b & 7, grp = b >> 3;
    const int nb = grp % gn, mbl = grp / gn;
    const int mb = mbl * 8 + xcd;
    if (mb >= gm) return;
    const int tm = mb * 128;
    const int tn = nb * 128;
    const int tid = threadIdx.x;
    const int w = tid >> 6, lane = tid & 63;

    // staging slot mapping: off16 = r*256 + w*64 + lane (16B slots)
    const int off0 = w * 64 + lane;
    const int row0 = off0 >> 2, q0 = off0 & 3;
    const int qg0 = q0 ^ ((row0 >> 1) & 3);
    const int off1 = 256 + w * 64 + lane;
    const int row1 = off1 >> 2, q1 = off1 & 3;
    const int qg1 = q1 ^ ((row1 >> 1) & 3);

    const int ar0 = min(tm + row0, M - 1), ar1 = min(tm + row1, M - 1);
    const int bn0 = min(tn + row0, Nc - 1), bn1 = min(tn + row1, Nc - 1);
    const unsigned short* pa0 = A + (size_t)ar0 * K + qg0 * 8;
    const unsigned short* pa1 = A + (size_t)ar1 * K + qg1 * 8;
    const unsigned short* pb0 = Bt + (size_t)bn0 * K + qg0 * 8;
    const unsigned short* pb1 = Bt + (size_t)bn1 * K + qg1 * 8;
    // wave-uniform LDS bases (HW adds lane*16)
    unsigned short* lA0 = As + (size_t)(w * 64) * 8;
    unsigned short* lA1 = As + (size_t)(256 + w * 64) * 8;
    unsigned short* lB0 = Bs + (size_t)(w * 64) * 8;
    unsigned short* lB1 = Bs + (size_t)(256 + w * 64) * 8;

    // fragment LDS read pointers
    const int m0 = (w & 1) * 64, n0 = (w >> 1) * 64;
    const int fr = lane & 15, Q = lane >> 4;
    const unsigned short* aptr[4];
    const unsigned short* bptr[4];
    #pragma unroll
    for (int i = 0; i < 4; ++i) {
        int ra = m0 + i * 16 + fr;
        aptr[i] = As + (ra * 64 + ((Q ^ ((ra >> 1) & 3)) * 16)) / 2;
        int rb = n0 + i * 16 + fr;
        bptr[i] = Bs + (rb * 64 + ((Q ^ ((rb >> 1) & 3)) * 16)) / 2;
    }

    f32x4 acc[4][4] = {};
    for (int kk = 0; kk < K; kk += 32) {
        async_copy16(pa0 + kk, lA0);
        async_copy16(pa1 + kk, lA1);
        async_copy16(pb0 + kk, lB0);
        async_copy16(pb1 + kk, lB1);
        __syncthreads();
        bf16x8 af[4], bfr[4];
        #pragma unroll
        for (int i = 0; i < 4; ++i) {
            af[i]  = *(const bf16x8*)aptr[i];
            bfr[i] = *(const bf16x8*)bptr[i];
        }
        #pragma unroll
        for (int mi = 0; mi < 4; ++mi)
            #pragma unroll
            for (int ni = 0; ni < 4; ++ni)
                acc[mi][ni] = __builtin_amdgcn_mfma_f32_16x16x32_bf16(
                    af[mi], bfr[ni], acc[mi][ni], 0, 0, 0);
        __syncthreads();
    }

    // epilogue: C/D layout col=lane&15, row=(lane>>4)*4+reg
    #pragma unroll
    for (int mi = 0; mi < 4; ++mi) {
        #pragma unroll
        for (int ni = 0; ni < 4; ++ni) {
            int col = tn + n0 + ni * 16 + fr;
            #pragma unroll
            for (int r = 0; r < 4; ++r) {
                int row = tm + m0 + mi * 16 + Q * 4 + r;
                if (row < M && col < Nc)
                    C[(size_t)row * Nc + col] = f2b(acc[mi][ni][r]);
            }
        }
    }
}

// ---------------- x -> bf16 conversion (+ fold in deg zeroing) ------------
__global__ __launch_bounds__(256) void cvt_f2b_degzero(
    const float* __restrict__ in, unsigned short* __restrict__ outp,
    int total4, int* __restrict__ deg, int n)
{
    int i = blockIdx.x * 256 + threadIdx.x;
    if (i < n) deg[i] = 0;
    if (i >= total4) return;
    float4 v = ((const float4*)in)[i];
    ushort4 o = make_ushort4(f2b(v.x), f2b(v.y), f2b(v.z), f2b(v.w));
    ((ushort4*)outp)[i] = o;
}

// ---- all 4 layers' weights -> transposed concatenated bf16 in one pass ---
// WT layout (shorts): L0 @ 0 (1024*512), L1 @ 524288 (256*512),
//                     L2 @ 655360 (256*512), L3 @ 786432 (256*64)
__global__ __launch_bounds__(256) void cvt_wt_all(
    const float* __restrict__ Wl0, const float* __restrict__ Wr0,
    const float* __restrict__ Wl1, const float* __restrict__ Wr1,
    const float* __restrict__ Wl2, const float* __restrict__ Wr2,
    const float* __restrict__ Wl3, const float* __restrict__ Wr3,
    unsigned short* __restrict__ WT)
{
    int id = blockIdx.x * 256 + threadIdx.x;
    const float *Wl, *Wr; int fin, HC, local; unsigned short* dst;
    if (id < 524288)      { Wl = Wl0; Wr = Wr0; fin = 1024; HC = 256; dst = WT;          local = id; }
    else if (id < 655360) { Wl = Wl1; Wr = Wr1; fin = 256;  HC = 256; dst = WT + 524288; local = id - 524288; }
    else if (id < 786432) { Wl = Wl2; Wr = Wr2; fin = 256;  HC = 256; dst = WT + 655360; local = id - 655360; }
    else if (id < 802816) { Wl = Wl3; Wr = Wr3; fin = 256;  HC = 32;  dst = WT + 786432; local = id - 786432; }
    else return;
    int n = local / fin, k = local - n * fin;
    float v = (n < HC) ? Wl[(size_t)k * HC + n] : Wr[(size_t)k * HC + (n - HC)];
    dst[local] = f2b(v);
}

// ======================= CSR construction (per call) ======================
__global__ __launch_bounds__(256) void deg_count(
    const int* __restrict__ ei, int* __restrict__ deg, int E0, int E)
{
    int e = blockIdx.x * 256 + threadIdx.x;
    if (e >= E) return;
    int d = (e < E0) ? ei[E0 + e] : e - E0;
    atomicAdd(deg + d, 1);
}

__global__ __launch_bounds__(256) void scan_blocks(
    const int* __restrict__ deg, int* __restrict__ rp,
    int* __restrict__ bsums, int n)
{
    __shared__ int sm[256];
    int base = blockIdx.x * 1024;
    int t = threadIdx.x;
    int i0 = base + t * 4;
    int v0 = (i0 + 0 < n) ? deg[i0 + 0] : 0;
    int v1 = (i0 + 1 < n) ? deg[i0 + 1] : 0;
    int v2 = (i0 + 2 < n) ? deg[i0 + 2] : 0;
    int v3 = (i0 + 3 < n) ? deg[i0 + 3] : 0;
    int tsum = v0 + v1 + v2 + v3;
    sm[t] = tsum;
    __syncthreads();
    for (int off = 1; off < 256; off <<= 1) {
        int val = (t >= off) ? sm[t - off] : 0;
        __syncthreads();
        sm[t] += val;
        __syncthreads();
    }
    int exb = sm[t] - tsum;
    if (t == 255) bsums[blockIdx.x] = sm[255];
    if (i0 + 0 < n) rp[i0 + 0] = exb;
    if (i0 + 1 < n) rp[i0 + 1] = exb + v0;
    if (i0 + 2 < n) rp[i0 + 2] = exb + v0 + v1;
    if (i0 + 3 < n) rp[i0 + 3] = exb + v0 + v1 + v2;
}

__global__ void scan_bsums(int* __restrict__ bsums, int nb)
{
    __shared__ int sm[64];
    int t = threadIdx.x;
    int v = (t < nb) ? bsums[t] : 0;
    sm[t] = v;
    __syncthreads();
    for (int off = 1; off < 64; off <<= 1) {
        int val = (t >= off) ? sm[t - off] : 0;
        __syncthreads();
        sm[t] += val;
        __syncthreads();
    }
    if (t < nb) bsums[t] = sm[t] - v;
}

__global__ __launch_bounds__(256) void scan_finalize(
    int* __restrict__ rp, int* __restrict__ cur,
    const int* __restrict__ bsums, int n)
{
    int i = blockIdx.x * 256 + threadIdx.x;
    if (i < n) {
        int v = rp[i] + bsums[i >> 10];
        rp[i] = v;
        cur[i] = v;
    }
}

__global__ __launch_bounds__(256) void csr_fill(
    const int* __restrict__ ei, int* __restrict__ cur,
    int* __restrict__ csrc, int E0, int E)
{
    int e = blockIdx.x * 256 + threadIdx.x;
    if (e >= E) return;
    int s, d;
    if (e < E0) { s = ei[e]; d = ei[E0 + e]; } else { s = e - E0; d = s; }
    int pos = atomicAdd(cur + d, 1);
    csrc[pos] = s;
}

// ====== chunked online-softmax update, 8 features/lane (HC=256 layers) ====
// T rows prefetched into registers unconditionally (SROA-safe), then consumed
// serially. Head reduction = 16-lane butterfly (feats 0-127 -> lanes 0-15).
template<int T>
__device__ __forceinline__ void gat_chunk8(
    const unsigned short* __restrict__ xlr, const int* __restrict__ cp,
    int fo, const float* bx, const float* wv,
    float& m, float& l, float* acc)
{
    int idx[T];
    #pragma unroll
    for (int t = 0; t < T; ++t) idx[t] = cp[t];
    u16x8 rb[T];
    #pragma unroll
    for (int t = 0; t < T; ++t)
        rb[t] = *(const u16x8*)(xlr + (size_t)idx[t] * 512 + fo);
    #pragma unroll
    for (int t = 0; t < T; ++t) {
        float a[8];
        #pragma unroll
        for (int i = 0; i < 8; ++i) a[i] = b2f(rb[t][i]);
        float dot = 0.f;
        #pragma unroll
        for (int i = 0; i < 8; ++i) {
            float y = a[i] + bx[i];
            y = (y > 0.f) ? y : NEG_SLOPE * y;
            dot += y * wv[i];
        }
        #pragma unroll
        for (int mk = 1; mk < 16; mk <<= 1) dot += __shfl_xor(dot, mk, 64);
        float mn = fmaxf(m, dot);
        float scale = __expf(m - mn);   // first edge: exp(-inf) = 0
        float p = __expf(dot - mn);
        l = l * scale + p;
        #pragma unroll
        for (int i = 0; i < 8; ++i) acc[i] = acc[i] * scale + p * a[i];
        m = mn;
    }
}

// ====== fused GATv2 attention + aggregation, HC=256 (H=2,C=128), bf16 =====
// TWO nodes per wave (one per 32-lane half); 8 feats/lane (16B gathers);
// lanes 0-15 of each half = head 0, 16-31 = head 1. Online softmax, 0 atomics.
__global__ __launch_bounds__(256) void aggr_csr_256(
    const unsigned short* __restrict__ xlr,
    const float* __restrict__ att, const float* __restrict__ bias,
    const int* __restrict__ csrc, const int* __restrict__ rp,
    const int* __restrict__ deg, unsigned short* __restrict__ outb, int N)
{
    int node = blockIdx.x * 8 + (threadIdx.x >> 5);
    if (node >= N) return;
    int fo = (threadIdx.x & 31) * 8;
    u16x8 bu = *(const u16x8*)(xlr + (size_t)node * 512 + 256 + fo);
    float bx[8], wv[8], acc[8];
    #pragma unroll
    for (int i = 0; i < 8; ++i) { bx[i] = b2f(bu[i]); acc[i] = 0.f; }
    *(float4*)(wv)     = *(const float4*)(att + fo);
    *(float4*)(wv + 4) = *(const float4*)(att + fo + 4);
    int start = rp[node];
    int g = deg[node];
    const int* cp = csrc + start;
    float m = -INFINITY, l = 0.f;
    int j = 0;
    while (j + 8 <= g) { gat_chunk8<8>(xlr, cp + j, fo, bx, wv, m, l, acc); j += 8; }
    if (j + 4 <= g)    { gat_chunk8<4>(xlr, cp + j, fo, bx, wv, m, l, acc); j += 4; }
    if (j + 2 <= g)    { gat_chunk8<2>(xlr, cp + j, fo, bx, wv, m, l, acc); j += 2; }
    if (j < g)         { gat_chunk8<1>(xlr, cp + j, fo, bx, wv, m, l, acc); }
    float inv = 1.f / l;
    float bi[8];
    *(float4*)(bi)     = *(const float4*)(bias + fo);
    *(float4*)(bi + 4) = *(const float4*)(bias + fo + 4);
    u16x8 o;
    #pragma unroll
    for (int i = 0; i < 8; ++i) o[i] = f2b(acc[i] * inv + bi[i]);
    *(u16x8*)(outb + (size_t)node * 256 + fo) = o;
}

// ========== chunked update, 4 features/lane (final HC=32 layer) ===========
template<int T, int STRIDE, int SHW>
__device__ __forceinline__ void gat_chunk(
    const unsigned short* __restrict__ xlr, const int* __restrict__ cp,
    int laneoff, float bx, float by, float bz, float bw, float4 wv,
    float& m, float& l, float4& acc)
{
    int idx[T];
    #pragma unroll
    for (int t = 0; t < T; ++t) idx[t] = cp[t];
    ushort4 rb[T];
    #pragma unroll
    for (int t = 0; t < T; ++t)
        rb[t] = *(const ushort4*)(xlr + (size_t)idx[t] * STRIDE + laneoff);
    #pragma unroll
    for (int t = 0; t < T; ++t) {
        float ax = b2f(rb[t].x), ay = b2f(rb[t].y);
        float az = b2f(rb[t].z), aw = b2f(rb[t].w);
        float y, dot = 0.f;
        y = ax + bx; y = (y > 0.f) ? y : NEG_SLOPE * y; dot += y * wv.x;
        y = ay + by; y = (y > 0.f) ? y : NEG_SLOPE * y; dot += y * wv.y;
        y = az + bz; y = (y > 0.f) ? y : NEG_SLOPE * y; dot += y * wv.z;
        y = aw + bw; y = (y > 0.f) ? y : NEG_SLOPE * y; dot += y * wv.w;
        #pragma unroll
        for (int mk = 1; mk < SHW; mk <<= 1) dot += __shfl_xor(dot, mk, 64);
        float mn = fmaxf(m, dot);
        float scale = __expf(m - mn);
        float p = __expf(dot - mn);
        l = l * scale + p;
        acc.x = acc.x * scale + p * ax;
        acc.y = acc.y * scale + p * ay;
        acc.z = acc.z * scale + p * az;
        acc.w = acc.w * scale + p * aw;
        m = mn;
    }
}

// ===== fused attention + aggregation, HC=32 (H=1,C=32), final layer =======
// 8 lanes per dst node; reads bf16 xlr [N][64] (xl=+0, xr=+32), writes fp32.
__global__ __launch_bounds__(256) void aggr_csr_32(
    const unsigned short* __restrict__ xlr,
    const float* __restrict__ att, const float* __restrict__ bias,
    const int* __restrict__ csrc, const int* __restrict__ rp,
    const int* __restrict__ deg, float* __restrict__ out, int N)
{
    int node = blockIdx.x * 32 + (threadIdx.x >> 3);
    if (node >= N) return;
    int lane8 = threadIdx.x & 7;
    int laneoff = lane8 * 4;
    ushort4 bu = *(const ushort4*)(xlr + (size_t)node * 64 + 32 + laneoff);
    float bx = b2f(bu.x), by = b2f(bu.y), bz = b2f(bu.z), bw = b2f(bu.w);
    float4 wv = *(const float4*)(att + laneoff);
    int start = rp[node];
    int g = deg[node];
    const int* cp = csrc + start;
    float m = -INFINITY, l = 0.f;
    float4 acc = make_float4(0.f, 0.f, 0.f, 0.f);
    int j = 0;
    while (j + 8 <= g) {
        gat_chunk<8, 64, 8>(xlr, cp + j, laneoff, bx, by, bz, bw, wv, m, l, acc);
        j += 8;
    }
    if (j + 4 <= g) {
        gat_chunk<4, 64, 8>(xlr, cp + j, laneoff, bx, by, bz, bw, wv, m, l, acc);
        j += 4;
    }
    if (j + 2 <= g) {
        gat_chunk<2, 64, 8>(xlr, cp + j, laneoff, bx, by, bz, bw, wv, m, l, acc);
        j += 2;
    }
    if (j < g) {
        gat_chunk<1, 64, 8>(xlr, cp + j, laneoff, bx, by, bz, bw, wv, m, l, acc);
    }
    float inv = 1.f / l;
    float4 bi = *(const float4*)(bias + laneoff);
    float4 o;
    o.x = acc.x * inv + bi.x;
    o.y = acc.y * inv + bi.y;
    o.z = acc.z * inv + bi.z;
    o.w = acc.w * inv + bi.w;
    *(float4*)(out + (size_t)node * 32 + laneoff) = o;
}

extern "C" void kernel_launch(void* const* d_in, const int* in_sizes, int n_in,
                              void* d_out, int out_size, void* d_ws, size_t ws_size,
                              hipStream_t stream)
{
    const float* x  = (const float*)d_in[0];
    const int*   ei = (const int*)d_in[1];
    const float* Wl[4]   = {(const float*)d_in[2], (const float*)d_in[6], (const float*)d_in[10], (const float*)d_in[14]};
    const float* Wr[4]   = {(const float*)d_in[3], (const float*)d_in[7], (const float*)d_in[11], (const float*)d_in[15]};
    const float* attw[4] = {(const float*)d_in[4], (const float*)d_in[8], (const float*)d_in[12], (const float*)d_in[16]};
    const float* bias[4] = {(const float*)d_in[5], (const float*)d_in[9], (const float*)d_in[13], (const float*)d_in[17]};
    float* outp = (float*)d_out;

    const int N  = in_sizes[0] / 1024;   // 50000
    const int E0 = in_sizes[1] / 2;      // 400000
    const int E  = E0 + N;               // +self loops
    const int NB = (N + 1023) / 1024;

    // workspace layout
    int* deg   = (int*)d_ws;                         // N
    int* rp    = deg + N;                            // N
    int* cur   = rp + N;                             // N
    int* bsums = cur + N;                            // 64
    int* csrc  = bsums + 64;                         // E
    unsigned short* WT  = (unsigned short*)(csrc + E);      // 802816 shorts
    unsigned short* xb  = WT + 802816;                      // N*1024 bf16
    unsigned short* hb  = xb;                               // alias: xb dead after L0 GEMM
    unsigned short* xlr = xb + (size_t)N * 1024;            // N*512 bf16
    const int wtOff[4] = {0, 524288, 655360, 786432};

    dim3 blk(256);

    // ---- x -> bf16 (+ deg zero), CSR build, weight conversion ----
    cvt_f2b_degzero<<<((size_t)N * 1024 / 4 + 255) / 256, blk, 0, stream>>>(
        x, xb, N * 1024 / 4, deg, N);
    deg_count<<<(E + 255) / 256, blk, 0, stream>>>(ei, deg, E0, E);
    scan_blocks<<<NB, blk, 0, stream>>>(deg, rp, bsums, N);
    scan_bsums<<<1, 64, 0, stream>>>(bsums, NB);
    scan_finalize<<<(N + 255) / 256, blk, 0, stream>>>(rp, cur, bsums, N);
    csr_fill<<<(E + 255) / 256, blk, 0, stream>>>(ei, cur, csrc, E0, E);
    cvt_wt_all<<<(802816 + 255) / 256, blk, 0, stream>>>(
        Wl[0], Wr[0], Wl[1], Wr[1], Wl[2], Wr[2], Wl[3], Wr[3], WT);

    const int gm = (N + 127) / 128;       // 391 m-tiles
    const int gm8 = (gm + 7) / 8;         // m-tile groups per XCD
    for (int l = 0; l < 4; ++l) {
        const int HC  = (l == 3) ? 32 : 256;
        const int fin = (l == 0) ? 1024 : 256;
        const int Nc  = 2 * HC;
        const int gn  = (Nc + 127) / 128;
        const unsigned short* Ain = (l == 0) ? xb : hb;

        gemm_bf16<<<8 * gn * gm8, blk, 0, stream>>>(
            Ain, WT + wtOff[l], xlr, N, fin, Nc, gm, gn);

        if (l < 3) {
            aggr_csr_256<<<(N + 7) / 8, blk, 0, stream>>>(
                xlr, attw[l], bias[l], csrc, rp, deg, hb, N);
        } else {
            aggr_csr_32<<<(N + 31) / 32, blk, 0, stream>>>(
                xlr, attw[l], bias[l], csrc, rp, deg, outp, N);
        }
    }
}